// Round 14
// baseline (3394.727 us; speedup 1.0000x reference)
//
#include <hip/hip_runtime.h>
#include <math.h>

#define Nn 8192

// f32 scratch layout in d_ws (proven >= 207KB; we use ~165KB)
static constexpr int W1o = 0;            // 128 (unused now, kept for layout)
static constexpr int W2o = 128;          // 128
static constexpr int S1o = 256;          // 8192
static constexpr int S2o = S1o + Nn;     // 8448
static constexpr int Mo  = S2o + Nn;     // 16640: row max of Rn -> later kcutA
static constexpr int Zo  = Mo + Nn;      // 24832: row sum of P  -> later kcutB
static constexpr int RRo = Zo + Nn;      // 33024: row reductions -> later kcutC
static constexpr int STo = RRo + Nn;     // 41216: mu, sig, thr
static constexpr int CNTo = STo + 8;     // 41224: 3 uint counters (as float slots)

typedef float nfloat4 __attribute__((ext_vector_type(4)));  // clang-native vec4

// ---- bit-exact f32 helpers (identical to round 7-13 winner) ----
__device__ __forceinline__ float lrelu32(float z) {
    return (z >= 0.0f) ? z : __fmul_rn(0.01f, z);
}
__device__ __forceinline__ float exp32cr(float x) {
    return (float)exp((double)x);   // MUST stay: margins are defined by this
}
__device__ float blas_dot(const float* __restrict__ a, const float* __restrict__ x, int n) {
    float lane[8];
#pragma unroll
    for (int l = 0; l < 8; ++l) lane[l] = 0.0f;
    for (int k = 0; k < n; k += 8) {
#pragma unroll
        for (int l = 0; l < 8; ++l) lane[l] = __fmaf_rn(a[k + l], x[k + l], lane[l]);
    }
    float s0 = __fadd_rn(lane[0], lane[4]);
    float s1 = __fadd_rn(lane[1], lane[5]);
    float s2 = __fadd_rn(lane[2], lane[6]);
    float s3 = __fadd_rn(lane[3], lane[7]);
    return __fadd_rn(__fadd_rn(s0, s1), __fadd_rn(s2, s3));
}

// sortable-key bijection for f32 (monotone with float order on finites)
__device__ __forceinline__ unsigned f2key(float f) {
    unsigned u = __float_as_uint(f);
    return (u & 0x80000000u) ? ~u : (u | 0x80000000u);
}
__device__ __forceinline__ float key2f(unsigned k) {
    unsigned u = (k & 0x80000000u) ? (k & 0x7FFFFFFFu) : ~k;
    return __uint_as_float(u);
}

// ---- shared reduction tail: red[512] -> leaf-combine -> 6-level tree ----
#define ROW_REDUCE_TAIL(RESULT_STMT)                                          \
    {                                                                         \
        __syncthreads();                                                      \
        if (t < 64) {                                                         \
            float sl = __fadd_rn(__fadd_rn(red[t * 8 + 0], red[t * 8 + 1]),   \
                                 __fadd_rn(red[t * 8 + 2], red[t * 8 + 3]));  \
            float sr = __fadd_rn(__fadd_rn(red[t * 8 + 4], red[t * 8 + 5]),   \
                                 __fadd_rn(red[t * 8 + 6], red[t * 8 + 7]));  \
            LA[t] = __fadd_rn(sl, sr);                                        \
        }                                                                     \
        __syncthreads();                                                      \
        {                                                                     \
            float* src = LA;                                                  \
            float* dst = LB;                                                  \
            for (int s = 32; s >= 1; s >>= 1) {                               \
                if (t < s) dst[t] = __fadd_rn(src[2 * t], src[2 * t + 1]);    \
                __syncthreads();                                              \
                float* tmp = src; src = dst; dst = tmp;                       \
            }                                                                 \
            if (t == 0) { RESULT_STMT; }                                      \
        }                                                                     \
    }

// ---- last-block global tree (bit-identical to k_tree: (2i,2i+1) levels) ----
// A[8192], B[4096] in LDS; 512 threads; returns total in A-slot src[0].
#define GLOBAL_TREE_8192(SRCPTR, TOTALVAR)                                    \
    {                                                                         \
        for (int idx = t; idx < 8192; idx += 512) A[idx] = (SRCPTR)[idx];     \
        __syncthreads();                                                      \
        float* src = A;                                                       \
        float* dst = B;                                                       \
        for (int s = 4096; s >= 1; s >>= 1) {                                 \
            for (int idx = t; idx < s; idx += 512)                            \
                dst[idx] = __fadd_rn(src[2 * idx], src[2 * idx + 1]);         \
            __syncthreads();                                                  \
            float* tmp = src; src = dst; dst = tmp;                           \
        }                                                                     \
        TOTALVAR = src[0];                                                    \
    }

// K1: fused w + s. 32 blocks x 256. Each block redundantly computes w1/w2
// (bit-identical blas_dot) into LDS, then its 256 rows. Zeroes counters.
__global__ __launch_bounds__(256) void k_s(const float* __restrict__ X,
                                           const float* __restrict__ Wr,
                                           const float* __restrict__ ar,
                                           float* __restrict__ scr) {
    __shared__ float w1[128], w2[128];
    int t = threadIdx.x;
    if (blockIdx.x == 0 && t < 3)
        reinterpret_cast<unsigned*>(scr + CNTo)[t] = 0u;
    if (t < 128) {
        w1[t] = blas_dot(Wr + t * 64, ar, 64);
        w2[t] = blas_dot(Wr + (128 + t) * 64, ar, 64);
    }
    __syncthreads();
    int i = blockIdx.x * 256 + t;
    scr[S1o + i] = blas_dot(X + i * 128, w1, 128);
    scr[S2o + i] = blas_dot(X + i * 128, w2, 128);
}

// per-row stats pass + last-block global tree -> mu (MODE 0) / sig (MODE 1).
template <int MODE>
__global__ __launch_bounds__(512) void k_stats(float* __restrict__ scr) {
    __shared__ float red[512];
    __shared__ float LA[64], LB[32];
    __shared__ float A[8192];
    __shared__ float B[4096];
    __shared__ unsigned ticket;
    float* rowred = scr + RRo;
    int i = blockIdx.x, t = threadIdx.x;
    int l = t >> 3, c = t & 7;
    const float* s2 = scr + S2o;
    float s1i = scr[S1o + i];
    float mu = (MODE == 1) ? scr[STo] : 0.0f;
    int ebase = l * 128 + c;
    float r;
    if (MODE == 0) {
        r = lrelu32(__fadd_rn(s1i, s2[ebase]));
#pragma unroll
        for (int k = 1; k < 16; ++k)
            r = __fadd_rn(r, lrelu32(__fadd_rn(s1i, s2[ebase + 8 * k])));
    } else {
        float d0 = __fsub_rn(lrelu32(__fadd_rn(s1i, s2[ebase])), mu);
        r = __fmul_rn(d0, d0);
#pragma unroll
        for (int k = 1; k < 16; ++k) {
            float d = __fsub_rn(lrelu32(__fadd_rn(s1i, s2[ebase + 8 * k])), mu);
            r = __fadd_rn(r, __fmul_rn(d, d));
        }
    }
    red[t] = r;
    ROW_REDUCE_TAIL(rowred[i] = src[0])
    // last finished block reduces all rows
    __threadfence();
    if (t == 0)
        ticket = atomicAdd(reinterpret_cast<unsigned*>(scr + CNTo) + MODE, 1u);
    __syncthreads();
    if (ticket == Nn - 1) {
        __threadfence();
        float total;
        GLOBAL_TREE_8192(rowred, total)
        if (t == 0) {
            if (MODE == 0) {
                scr[STo] = __fdiv_rn(total, 67108864.0f);
            } else {
                float var = __fdiv_rn(total, 67108864.0f);
                scr[STo + 1] = __fadd_rn(__fsqrt_rn(var), 1e-5f);
            }
        }
    }
}

// Fused per-row: max(Rn)->Mi; P in registers; Zi; E-sums; last block -> thr.
__global__ __launch_bounds__(512) void k_MZE(float* __restrict__ scr) {
    __shared__ float red[512];
    __shared__ float LA[64], LB[32];
    __shared__ float A[8192];
    __shared__ float B[4096];
    __shared__ float Zsh;
    __shared__ unsigned ticket;
    float* rowred = scr + RRo;
    int i = blockIdx.x, t = threadIdx.x;
    int l = t >> 3, c = t & 7;
    const float* s2 = scr + S2o;
    float s1i = scr[S1o + i];
    float mu = scr[STo], sig = scr[STo + 1];
    int ebase = l * 128 + c;

    // phase A: Rn in registers + row max (order-free)
    float rn[16];
    float mx = -3.4e38f;
#pragma unroll
    for (int k = 0; k < 16; ++k) {
        float Rn = __fdiv_rn(__fsub_rn(lrelu32(__fadd_rn(s1i, s2[ebase + 8 * k])), mu), sig);
        rn[k] = Rn;
        mx = fmaxf(mx, Rn);
    }
    red[t] = mx;
    __syncthreads();
    for (int s = 256; s >= 1; s >>= 1) {
        if (t < s) red[t] = fmaxf(red[t], red[t + s]);
        __syncthreads();
    }
    float Mi = red[0];
    __syncthreads();

    // phase B: P in registers, chain sum (exact NP order)
    float p[16];
    p[0] = exp32cr(__fsub_rn(rn[0], Mi));
    float r = p[0];
#pragma unroll
    for (int k = 1; k < 16; ++k) {
        p[k] = exp32cr(__fsub_rn(rn[k], Mi));
        r = __fadd_rn(r, p[k]);
    }
    red[t] = r;
    ROW_REDUCE_TAIL(Zsh = src[0]; scr[Zo + i] = src[0]; scr[Mo + i] = Mi)
    __syncthreads();
    float Zi = Zsh;

    // phase C: E = P/Zi, same chain + leaf + tree order
    float e = __fdiv_rn(p[0], Zi);
#pragma unroll
    for (int k = 1; k < 16; ++k)
        e = __fadd_rn(e, __fdiv_rn(p[k], Zi));
    red[t] = e;
    ROW_REDUCE_TAIL(rowred[i] = src[0])

    // last finished block: global tree over rowredE -> thr
    __threadfence();
    if (t == 0)
        ticket = atomicAdd(reinterpret_cast<unsigned*>(scr + CNTo) + 2, 1u);
    __syncthreads();
    if (ticket == Nn - 1) {
        __threadfence();
        float total;
        GLOBAL_TREE_8192(rowred, total)
        if (t == 0) {
            float mean = __fdiv_rn(total, 67108864.0f);
            scr[STo + 2] = __fdiv_rn(mean, 0.5f);
        }
    }
}

// One thread per (row, search): 3 monotone-cutoff binary searches. All
// searches take exactly 32 uniform iterations. Writes cut keys over Mo/Zo/RRo.
// Reads Mi/Zi BEFORE any thread overwrites: thread handling (i,w) reads
// scr[Mo+i]/scr[Zo+i] first — but another thread may write kcut to the same
// slots concurrently! Avoid: stage reads and writes in separate kernels? No:
// same kernel, different (i,w) threads touch only row i's slots; all three
// (i,0),(i,1),(i,2) threads read Mi,Zi then write distinct slots. A thread of
// row i never touches row j's slots, but (i,0) writes Mo+i while (i,1) still
// needs to READ Mo+i. Fix: each thread re-reads Mi,Zi at start; then a
// __threadfence-free hazard remains across threads of the SAME row in
// DIFFERENT waves. Solution: keep all 3 searches in ONE thread per row for
// the writeback... simpler: grid-stride so one thread does row i's 3 searches
// (as r13) but grid widened to 64 blocks for latency: rows split 8192/16384.
__global__ __launch_bounds__(128) void k_cut(float* __restrict__ scr) {
    int i = blockIdx.x * 128 + threadIdx.x;
    if (i >= Nn) return;
    float s1i = scr[S1o + i];
    float mu = scr[STo], sig = scr[STo + 1], thr = scr[STo + 2];
    float Mi = scr[Mo + i], Zi = scr[Zo + i];
    double thr_d = (double)thr;
    unsigned kcut[3];
#pragma unroll
    for (int w = 0; w < 3; ++w) {
        unsigned lo = 0x00800000u;   // key(-FLT_MAX)
        unsigned hi = 0xFF800000u;   // key(+inf), exclusive
        while (lo < hi) {
            unsigned mid = lo + ((hi - lo) >> 1);
            float s2v = key2f(mid);
            float Rn = __fdiv_rn(__fsub_rn(lrelu32(__fadd_rn(s1i, s2v)), mu), sig);
            float P = exp32cr(__fsub_rn(Rn, Mi));
            float E = __fdiv_rn(P, Zi);
            double m = ((double)E - thr_d) / thr_d;
            bool pred = (w == 0) ? (m >= -2.8e-8)
                      : (w == 1) ? (m > 2.8e-8)
                                 : (m >= 1.75e-7);
            if (pred) hi = mid; else lo = mid + 1;
        }
        kcut[w] = lo;
    }
    scr[Mo + i]  = __uint_as_float(kcut[0]);
    scr[Zo + i]  = __uint_as_float(kcut[1]);
    scr[RRo + i] = __uint_as_float(kcut[2]);
}

// Pure streaming writer: 1024 blocks x 8 rows; nontemporal vec4 stores.
__global__ __launch_bounds__(256) void k_out(const float* __restrict__ scr,
                                             float* __restrict__ out) {
    int t = threadIdx.x;
    int r0 = blockIdx.x * 8;
    const float* s2 = scr + S2o;
    unsigned kA[8], kB[8], kC[8];
    long long rowbase[8];
#pragma unroll
    for (int rr = 0; rr < 8; ++rr) {
        int i = r0 + rr;
        kA[rr] = __float_as_uint(scr[Mo + i]);
        kB[rr] = __float_as_uint(scr[Zo + i]);
        kC[rr] = __float_as_uint(scr[RRo + i]);
        rowbase[rr] = (long long)i * Nn;
    }
    for (int ch = 0; ch < 8; ++ch) {
        int j0 = ch * 1024 + t * 4;
        nfloat4 sv = *reinterpret_cast<const nfloat4*>(s2 + j0);
        unsigned k0 = f2key(sv.x), k1 = f2key(sv.y), k2 = f2key(sv.z), k3 = f2key(sv.w);
#pragma unroll
        for (int rr = 0; rr < 8; ++rr) {
            unsigned a = kA[rr], b = kB[rr], cc = kC[rr];
            nfloat4 r;
            r.x = (k0 < a) ? 0.0f : (k0 < b) ? 1.0f : (k0 < cc) ? 0.0f : 1.0f;
            r.y = (k1 < a) ? 0.0f : (k1 < b) ? 1.0f : (k1 < cc) ? 0.0f : 1.0f;
            r.z = (k2 < a) ? 0.0f : (k2 < b) ? 1.0f : (k2 < cc) ? 0.0f : 1.0f;
            r.w = (k3 < a) ? 0.0f : (k3 < b) ? 1.0f : (k3 < cc) ? 0.0f : 1.0f;
            __builtin_nontemporal_store(r, reinterpret_cast<nfloat4*>(out + rowbase[rr] + j0));
        }
    }
}

extern "C" void kernel_launch(void* const* d_in, const int* in_sizes, int n_in,
                              void* d_out, int out_size, void* d_ws, size_t ws_size,
                              hipStream_t stream) {
    const float *X = nullptr, *Wr = nullptr, *ar = nullptr;
    for (int k = 0; k < n_in; ++k) {
        if      (in_sizes[k] == 1048576) X  = (const float*)d_in[k];
        else if (in_sizes[k] == 16384)   Wr = (const float*)d_in[k];
        else if (in_sizes[k] == 64)      ar = (const float*)d_in[k];
    }
    if (!X)  X  = (const float*)d_in[0];
    if (!Wr) Wr = (const float*)d_in[1];
    if (!ar) ar = (const float*)d_in[2];

    float* out = (float*)d_out;
    float* scr = (float*)d_ws;

    k_s       <<<32,   256, 0, stream>>>(X, Wr, ar, scr);
    k_stats<0><<<Nn,   512, 0, stream>>>(scr);
    k_stats<1><<<Nn,   512, 0, stream>>>(scr);
    k_MZE     <<<Nn,   512, 0, stream>>>(scr);
    k_cut     <<<64,   128, 0, stream>>>(scr);
    k_out     <<<1024, 256, 0, stream>>>(scr, out);
}

// Round 15
// 220.541 us; speedup vs baseline: 15.3927x; 15.3927x over previous
//
#include <hip/hip_runtime.h>
#include <math.h>

#define Nn 8192

// f32 scratch layout in d_ws (proven >= 207KB; we use ~165KB)
static constexpr int S1o = 256;          // 8192
static constexpr int S2o = S1o + Nn;     // 8448
static constexpr int Mo  = S2o + Nn;     // 16640: row max of Rn -> later kcutA
static constexpr int Zo  = Mo + Nn;      // 24832: row sum of P  -> later kcutB
static constexpr int RRo = Zo + Nn;      // 33024: row reductions -> later kcutC
static constexpr int STo = RRo + Nn;     // 41216: mu, sig, thr

typedef float nfloat4 __attribute__((ext_vector_type(4)));  // clang-native vec4

// ---- bit-exact f32 helpers (identical to round 7-13 winner) ----
__device__ __forceinline__ float lrelu32(float z) {
    return (z >= 0.0f) ? z : __fmul_rn(0.01f, z);
}
__device__ __forceinline__ float exp32cr(float x) {
    return (float)exp((double)x);   // MUST stay: margins are defined by this
}
__device__ float blas_dot(const float* __restrict__ a, const float* __restrict__ x, int n) {
    float lane[8];
#pragma unroll
    for (int l = 0; l < 8; ++l) lane[l] = 0.0f;
    for (int k = 0; k < n; k += 8) {
#pragma unroll
        for (int l = 0; l < 8; ++l) lane[l] = __fmaf_rn(a[k + l], x[k + l], lane[l]);
    }
    float s0 = __fadd_rn(lane[0], lane[4]);
    float s1 = __fadd_rn(lane[1], lane[5]);
    float s2 = __fadd_rn(lane[2], lane[6]);
    float s3 = __fadd_rn(lane[3], lane[7]);
    return __fadd_rn(__fadd_rn(s0, s1), __fadd_rn(s2, s3));
}

// sortable-key bijection for f32 (monotone with float order on finites)
__device__ __forceinline__ unsigned f2key(float f) {
    unsigned u = __float_as_uint(f);
    return (u & 0x80000000u) ? ~u : (u | 0x80000000u);
}
__device__ __forceinline__ float key2f(unsigned k) {
    unsigned u = (k & 0x80000000u) ? (k & 0x7FFFFFFFu) : ~k;
    return __uint_as_float(u);
}

// ---- shared reduction tail: red[512] -> leaf-combine -> 6-level tree ----
#define ROW_REDUCE_TAIL(RESULT_STMT)                                          \
    {                                                                         \
        __syncthreads();                                                      \
        if (t < 64) {                                                         \
            float sl = __fadd_rn(__fadd_rn(red[t * 8 + 0], red[t * 8 + 1]),   \
                                 __fadd_rn(red[t * 8 + 2], red[t * 8 + 3]));  \
            float sr = __fadd_rn(__fadd_rn(red[t * 8 + 4], red[t * 8 + 5]),   \
                                 __fadd_rn(red[t * 8 + 6], red[t * 8 + 7]));  \
            LA[t] = __fadd_rn(sl, sr);                                        \
        }                                                                     \
        __syncthreads();                                                      \
        {                                                                     \
            float* src = LA;                                                  \
            float* dst = LB;                                                  \
            for (int s = 32; s >= 1; s >>= 1) {                               \
                if (t < s) dst[t] = __fadd_rn(src[2 * t], src[2 * t + 1]);    \
                __syncthreads();                                              \
                float* tmp = src; src = dst; dst = tmp;                       \
            }                                                                 \
            if (t == 0) { RESULT_STMT; }                                      \
        }                                                                     \
    }

// K1: fused w + s. 32 blocks x 256. Each block redundantly computes w1/w2
// (bit-identical blas_dot) into LDS, then its 256 rows. No atomics/fences.
__global__ __launch_bounds__(256) void k_s(const float* __restrict__ X,
                                           const float* __restrict__ Wr,
                                           const float* __restrict__ ar,
                                           float* __restrict__ scr) {
    __shared__ float w1[128], w2[128];
    int t = threadIdx.x;
    if (t < 128) {
        w1[t] = blas_dot(Wr + t * 64, ar, 64);
        w2[t] = blas_dot(Wr + (128 + t) * 64, ar, 64);
    }
    __syncthreads();
    int i = blockIdx.x * 256 + t;
    scr[S1o + i] = blas_dot(X + i * 128, w1, 128);
    scr[S2o + i] = blas_dot(X + i * 128, w2, 128);
}

// per-row stats pass, 512 threads = 64 leaves x 8 chains — NP_LEAF order.
template <int MODE>
__global__ __launch_bounds__(512) void k_rows_stat(const float* __restrict__ scr,
                                                   float* __restrict__ rowred) {
    __shared__ float red[512];
    __shared__ float LA[64], LB[32];
    int i = blockIdx.x, t = threadIdx.x;
    int l = t >> 3, c = t & 7;
    const float* s2 = scr + S2o;
    float s1i = scr[S1o + i];
    float mu = (MODE == 1) ? scr[STo] : 0.0f;
    int ebase = l * 128 + c;
    float r;
    if (MODE == 0) {
        r = lrelu32(__fadd_rn(s1i, s2[ebase]));
#pragma unroll
        for (int k = 1; k < 16; ++k)
            r = __fadd_rn(r, lrelu32(__fadd_rn(s1i, s2[ebase + 8 * k])));
    } else {
        float d0 = __fsub_rn(lrelu32(__fadd_rn(s1i, s2[ebase])), mu);
        r = __fmul_rn(d0, d0);
#pragma unroll
        for (int k = 1; k < 16; ++k) {
            float d = __fsub_rn(lrelu32(__fadd_rn(s1i, s2[ebase + 8 * k])), mu);
            r = __fadd_rn(r, __fmul_rn(d, d));
        }
    }
    red[t] = r;
    ROW_REDUCE_TAIL(rowred[i] = src[0])
}

template <int MODE>
__global__ __launch_bounds__(1024) void k_tree(const float* __restrict__ rowred,
                                               float* __restrict__ scr) {
    __shared__ float A[8192];
    __shared__ float B[4096];
    int t = threadIdx.x;  // 1024
    for (int idx = t; idx < 8192; idx += 1024) A[idx] = rowred[idx];
    __syncthreads();
    float* src = A;
    float* dst = B;
    for (int s = 4096; s >= 1; s >>= 1) {
        for (int idx = t; idx < s; idx += 1024)
            dst[idx] = __fadd_rn(src[2 * idx], src[2 * idx + 1]);
        __syncthreads();
        float* tmp = src; src = dst; dst = tmp;
    }
    if (t == 0) {
        float total = src[0];
        if (MODE == 0) {
            scr[STo] = __fdiv_rn(total, 67108864.0f);
        } else if (MODE == 1) {
            float var = __fdiv_rn(total, 67108864.0f);
            scr[STo + 1] = __fadd_rn(__fsqrt_rn(var), 1e-5f);
        } else {
            float mean = __fdiv_rn(total, 67108864.0f);
            scr[STo + 2] = __fdiv_rn(mean, 0.5f);
        }
    }
}

// Fused per-row: max(Rn) -> Mi; P in REGISTERS; Zi; E-sums. r13 byte-for-byte.
__global__ __launch_bounds__(512) void k_MZE(float* __restrict__ scr,
                                             float* __restrict__ rowred) {
    __shared__ float red[512];
    __shared__ float LA[64], LB[32];
    __shared__ float Zsh;
    int i = blockIdx.x, t = threadIdx.x;
    int l = t >> 3, c = t & 7;
    const float* s2 = scr + S2o;
    float s1i = scr[S1o + i];
    float mu = scr[STo], sig = scr[STo + 1];
    int ebase = l * 128 + c;

    // phase A: Rn in registers + row max (order-free)
    float rn[16];
    float mx = -3.4e38f;
#pragma unroll
    for (int k = 0; k < 16; ++k) {
        float Rn = __fdiv_rn(__fsub_rn(lrelu32(__fadd_rn(s1i, s2[ebase + 8 * k])), mu), sig);
        rn[k] = Rn;
        mx = fmaxf(mx, Rn);
    }
    red[t] = mx;
    __syncthreads();
    for (int s = 256; s >= 1; s >>= 1) {
        if (t < s) red[t] = fmaxf(red[t], red[t + s]);
        __syncthreads();
    }
    float Mi = red[0];
    __syncthreads();

    // phase B: P in registers, chain sum (exact NP order)
    float p[16];
    p[0] = exp32cr(__fsub_rn(rn[0], Mi));
    float r = p[0];
#pragma unroll
    for (int k = 1; k < 16; ++k) {
        p[k] = exp32cr(__fsub_rn(rn[k], Mi));
        r = __fadd_rn(r, p[k]);
    }
    red[t] = r;
    ROW_REDUCE_TAIL(Zsh = src[0]; scr[Zo + i] = src[0]; scr[Mo + i] = Mi)
    __syncthreads();
    float Zi = Zsh;

    // phase C: E = P/Zi, same chain + leaf + tree order
    float e = __fdiv_rn(p[0], Zi);
#pragma unroll
    for (int k = 1; k < 16; ++k)
        e = __fadd_rn(e, __fdiv_rn(p[k], Zi));
    red[t] = e;
    ROW_REDUCE_TAIL(rowred[i] = src[0])
}

// One thread per row; the 3 independent 32-step binary searches are
// INTERLEAVED so 3 exps are in flight (ILP) — latency-bound kernel ~3x.
// Probe sequence per search identical to r13 => identical cut keys.
// (Range < 2^32 => exactly 32 halvings; converged searches self-hold:
//  probe at lo==hi is always pred-true there, see r13 analysis.)
__global__ __launch_bounds__(256) void k_cut(float* __restrict__ scr) {
    int i = blockIdx.x * 256 + threadIdx.x;
    if (i >= Nn) return;
    float s1i = scr[S1o + i];
    float mu = scr[STo], sig = scr[STo + 1], thr = scr[STo + 2];
    float Mi = scr[Mo + i], Zi = scr[Zo + i];
    double thr_d = (double)thr;
    unsigned lo[3] = {0x00800000u, 0x00800000u, 0x00800000u};
    unsigned hi[3] = {0xFF800000u, 0xFF800000u, 0xFF800000u};
    for (int it = 0; it < 32; ++it) {
        unsigned mid[3];
        double m[3];
#pragma unroll
        for (int w = 0; w < 3; ++w) {
            mid[w] = lo[w] + ((hi[w] - lo[w]) >> 1);
            float s2v = key2f(mid[w]);
            float Rn = __fdiv_rn(__fsub_rn(lrelu32(__fadd_rn(s1i, s2v)), mu), sig);
            float P = exp32cr(__fsub_rn(Rn, Mi));
            float E = __fdiv_rn(P, Zi);
            m[w] = ((double)E - thr_d) / thr_d;
        }
        bool p0 = (m[0] >= -2.8e-8);
        bool p1 = (m[1] > 2.8e-8);
        bool p2 = (m[2] >= 1.75e-7);
        if (p0) hi[0] = mid[0]; else lo[0] = mid[0] + 1;
        if (p1) hi[1] = mid[1]; else lo[1] = mid[1] + 1;
        if (p2) hi[2] = mid[2]; else lo[2] = mid[2] + 1;
    }
    scr[Mo + i]  = __uint_as_float(lo[0]);
    scr[Zo + i]  = __uint_as_float(lo[1]);
    scr[RRo + i] = __uint_as_float(lo[2]);
}

// Pure streaming writer: 1024 blocks x 8 rows; nontemporal vec4 stores.
__global__ __launch_bounds__(256) void k_out(const float* __restrict__ scr,
                                             float* __restrict__ out) {
    int t = threadIdx.x;
    int r0 = blockIdx.x * 8;
    const float* s2 = scr + S2o;
    unsigned kA[8], kB[8], kC[8];
    long long rowbase[8];
#pragma unroll
    for (int rr = 0; rr < 8; ++rr) {
        int i = r0 + rr;
        kA[rr] = __float_as_uint(scr[Mo + i]);
        kB[rr] = __float_as_uint(scr[Zo + i]);
        kC[rr] = __float_as_uint(scr[RRo + i]);
        rowbase[rr] = (long long)i * Nn;
    }
    for (int ch = 0; ch < 8; ++ch) {
        int j0 = ch * 1024 + t * 4;
        nfloat4 sv = *reinterpret_cast<const nfloat4*>(s2 + j0);
        unsigned k0 = f2key(sv.x), k1 = f2key(sv.y), k2 = f2key(sv.z), k3 = f2key(sv.w);
#pragma unroll
        for (int rr = 0; rr < 8; ++rr) {
            unsigned a = kA[rr], b = kB[rr], cc = kC[rr];
            nfloat4 r;
            r.x = (k0 < a) ? 0.0f : (k0 < b) ? 1.0f : (k0 < cc) ? 0.0f : 1.0f;
            r.y = (k1 < a) ? 0.0f : (k1 < b) ? 1.0f : (k1 < cc) ? 0.0f : 1.0f;
            r.z = (k2 < a) ? 0.0f : (k2 < b) ? 1.0f : (k2 < cc) ? 0.0f : 1.0f;
            r.w = (k3 < a) ? 0.0f : (k3 < b) ? 1.0f : (k3 < cc) ? 0.0f : 1.0f;
            __builtin_nontemporal_store(r, reinterpret_cast<nfloat4*>(out + rowbase[rr] + j0));
        }
    }
}

extern "C" void kernel_launch(void* const* d_in, const int* in_sizes, int n_in,
                              void* d_out, int out_size, void* d_ws, size_t ws_size,
                              hipStream_t stream) {
    const float *X = nullptr, *Wr = nullptr, *ar = nullptr;
    for (int k = 0; k < n_in; ++k) {
        if      (in_sizes[k] == 1048576) X  = (const float*)d_in[k];
        else if (in_sizes[k] == 16384)   Wr = (const float*)d_in[k];
        else if (in_sizes[k] == 64)      ar = (const float*)d_in[k];
    }
    if (!X)  X  = (const float*)d_in[0];
    if (!Wr) Wr = (const float*)d_in[1];
    if (!ar) ar = (const float*)d_in[2];

    float* out = (float*)d_out;
    float* scr = (float*)d_ws;
    float* rowred = scr + RRo;

    k_s           <<<32,   256, 0, stream>>>(X, Wr, ar, scr);
    k_rows_stat<0><<<Nn,   512, 0, stream>>>(scr, rowred);
    k_tree<0>     <<<1,   1024, 0, stream>>>(rowred, scr);
    k_rows_stat<1><<<Nn,   512, 0, stream>>>(scr, rowred);
    k_tree<1>     <<<1,   1024, 0, stream>>>(rowred, scr);
    k_MZE         <<<Nn,   512, 0, stream>>>(scr, rowred);
    k_tree<2>     <<<1,   1024, 0, stream>>>(rowred, scr);
    k_cut         <<<32,   256, 0, stream>>>(scr);
    k_out         <<<1024, 256, 0, stream>>>(scr, out);
}

// Round 16
// 215.140 us; speedup vs baseline: 15.7791x; 1.0251x over previous
//
#include <hip/hip_runtime.h>
#include <math.h>

#define Nn 8192

// f32 scratch layout in d_ws (proven >= 207KB; we use ~165KB)
static constexpr int S1o = 256;          // 8192
static constexpr int S2o = S1o + Nn;     // 8448
static constexpr int Mo  = S2o + Nn;     // 16640: row max of Rn -> later kcutA
static constexpr int Zo  = Mo + Nn;      // 24832: row sum of P  -> later kcutB
static constexpr int RRo = Zo + Nn;      // 33024: row reductions -> later kcutC
static constexpr int STo = RRo + Nn;     // 41216: mu, sig, thr

typedef float nfloat4 __attribute__((ext_vector_type(4)));  // clang-native vec4

// ---- bit-exact f32 helpers ----
__device__ __forceinline__ float lrelu32(float z) {
    return (z >= 0.0f) ? z : __fmul_rn(0.01f, z);
}

// Branch-free f64 exp, rel err ~2^-49 (Cody-Waite + deg-13 Taylor Horner).
// Clamp keeps extreme probes well-defined with correct predicate signs
// (true exp saturates to 0/inf there; any huge/tiny value gives same sign).
__device__ __forceinline__ double exp_fast(double x) {
    x = fmin(fmax(x, -700.0), 700.0);
    const double INVLN2 = 1.44269504088896338700e+00;
    const double LN2HI  = 6.93147180369123816490e-01;  // 20 trailing zero bits
    const double LN2LO  = 1.90821492927058770002e-10;
    double nd = rint(x * INVLN2);
    double r  = fma(-nd, LN2HI, x);
    r = fma(-nd, LN2LO, r);
    double p = 1.56192069685862264622e-10;             // 1/13!
    p = fma(p, r, 2.08767569878680989792e-09);         // 1/12!
    p = fma(p, r, 2.50521083854417187751e-08);         // 1/11!
    p = fma(p, r, 2.75573192239858906526e-07);         // 1/10!
    p = fma(p, r, 2.75573192239858925110e-06);         // 1/9!
    p = fma(p, r, 2.48015873015873015873e-05);         // 1/8!
    p = fma(p, r, 1.98412698412698412698e-04);         // 1/7!
    p = fma(p, r, 1.38888888888888894069e-03);         // 1/6!
    p = fma(p, r, 8.33333333333333321769e-03);         // 1/5!
    p = fma(p, r, 4.16666666666666643537e-02);         // 1/4!
    p = fma(p, r, 1.66666666666666657415e-01);         // 1/3!
    p = fma(p, r, 5.00000000000000000000e-01);         // 1/2!
    p = fma(p, r, 1.0);                                // 1/1!
    p = fma(p, r, 1.0);                                // 1/0!
    long long n = (long long)nd;
    double sc = __longlong_as_double((n + 1023LL) << 52);
    return p * sc;
}
__device__ __forceinline__ float exp32cr(float x) {
    return (float)exp_fast((double)x);
}

__device__ float blas_dot(const float* __restrict__ a, const float* __restrict__ x, int n) {
    float lane[8];
#pragma unroll
    for (int l = 0; l < 8; ++l) lane[l] = 0.0f;
    for (int k = 0; k < n; k += 8) {
#pragma unroll
        for (int l = 0; l < 8; ++l) lane[l] = __fmaf_rn(a[k + l], x[k + l], lane[l]);
    }
    float s0 = __fadd_rn(lane[0], lane[4]);
    float s1 = __fadd_rn(lane[1], lane[5]);
    float s2 = __fadd_rn(lane[2], lane[6]);
    float s3 = __fadd_rn(lane[3], lane[7]);
    return __fadd_rn(__fadd_rn(s0, s1), __fadd_rn(s2, s3));
}

// sortable-key bijection for f32 (monotone with float order on finites)
__device__ __forceinline__ unsigned f2key(float f) {
    unsigned u = __float_as_uint(f);
    return (u & 0x80000000u) ? ~u : (u | 0x80000000u);
}
__device__ __forceinline__ float key2f(unsigned k) {
    unsigned u = (k & 0x80000000u) ? (k & 0x7FFFFFFFu) : ~k;
    return __uint_as_float(u);
}

// ---- shared reduction tail: red[512] -> leaf-combine -> 6-level tree ----
#define ROW_REDUCE_TAIL(RESULT_STMT)                                          \
    {                                                                         \
        __syncthreads();                                                      \
        if (t < 64) {                                                         \
            float sl = __fadd_rn(__fadd_rn(red[t * 8 + 0], red[t * 8 + 1]),   \
                                 __fadd_rn(red[t * 8 + 2], red[t * 8 + 3]));  \
            float sr = __fadd_rn(__fadd_rn(red[t * 8 + 4], red[t * 8 + 5]),   \
                                 __fadd_rn(red[t * 8 + 6], red[t * 8 + 7]));  \
            LA[t] = __fadd_rn(sl, sr);                                        \
        }                                                                     \
        __syncthreads();                                                      \
        {                                                                     \
            float* src = LA;                                                  \
            float* dst = LB;                                                  \
            for (int s = 32; s >= 1; s >>= 1) {                               \
                if (t < s) dst[t] = __fadd_rn(src[2 * t], src[2 * t + 1]);    \
                __syncthreads();                                              \
                float* tmp = src; src = dst; dst = tmp;                       \
            }                                                                 \
            if (t == 0) { RESULT_STMT; }                                      \
        }                                                                     \
    }

// K1: fused w + s. 32 blocks x 256.
__global__ __launch_bounds__(256) void k_s(const float* __restrict__ X,
                                           const float* __restrict__ Wr,
                                           const float* __restrict__ ar,
                                           float* __restrict__ scr) {
    __shared__ float w1[128], w2[128];
    int t = threadIdx.x;
    if (t < 128) {
        w1[t] = blas_dot(Wr + t * 64, ar, 64);
        w2[t] = blas_dot(Wr + (128 + t) * 64, ar, 64);
    }
    __syncthreads();
    int i = blockIdx.x * 256 + t;
    scr[S1o + i] = blas_dot(X + i * 128, w1, 128);
    scr[S2o + i] = blas_dot(X + i * 128, w2, 128);
}

// stats pass, 1024 blocks x 8 rows; s2 slice loaded ONCE into registers,
// reused across rows. Per-row chain/leaf/tree order identical to NP_LEAF.
template <int MODE>
__global__ __launch_bounds__(512) void k_rows_stat8(const float* __restrict__ scr,
                                                    float* __restrict__ rowred) {
    __shared__ float red[512];
    __shared__ float LA[64], LB[32];
    int r0 = blockIdx.x * 8, t = threadIdx.x;
    int l = t >> 3, c = t & 7;
    const float* s2 = scr + S2o;
    int ebase = l * 128 + c;
    float sv[16];
#pragma unroll
    for (int k = 0; k < 16; ++k) sv[k] = s2[ebase + 8 * k];
    float mu = (MODE == 1) ? scr[STo] : 0.0f;
    for (int rr = 0; rr < 8; ++rr) {
        float s1i = scr[S1o + r0 + rr];
        float r;
        if (MODE == 0) {
            r = lrelu32(__fadd_rn(s1i, sv[0]));
#pragma unroll
            for (int k = 1; k < 16; ++k)
                r = __fadd_rn(r, lrelu32(__fadd_rn(s1i, sv[k])));
        } else {
            float d0 = __fsub_rn(lrelu32(__fadd_rn(s1i, sv[0])), mu);
            r = __fmul_rn(d0, d0);
#pragma unroll
            for (int k = 1; k < 16; ++k) {
                float d = __fsub_rn(lrelu32(__fadd_rn(s1i, sv[k])), mu);
                r = __fadd_rn(r, __fmul_rn(d, d));
            }
        }
        red[t] = r;
        ROW_REDUCE_TAIL(rowred[r0 + rr] = src[0])
    }
}

template <int MODE>
__global__ __launch_bounds__(1024) void k_tree(const float* __restrict__ rowred,
                                               float* __restrict__ scr) {
    __shared__ float A[8192];
    __shared__ float B[4096];
    int t = threadIdx.x;  // 1024
    for (int idx = t; idx < 8192; idx += 1024) A[idx] = rowred[idx];
    __syncthreads();
    float* src = A;
    float* dst = B;
    for (int s = 4096; s >= 1; s >>= 1) {
        for (int idx = t; idx < s; idx += 1024)
            dst[idx] = __fadd_rn(src[2 * idx], src[2 * idx + 1]);
        __syncthreads();
        float* tmp = src; src = dst; dst = tmp;
    }
    if (t == 0) {
        float total = src[0];
        if (MODE == 0) {
            scr[STo] = __fdiv_rn(total, 67108864.0f);
        } else if (MODE == 1) {
            float var = __fdiv_rn(total, 67108864.0f);
            scr[STo + 1] = __fadd_rn(__fsqrt_rn(var), 1e-5f);
        } else {
            float mean = __fdiv_rn(total, 67108864.0f);
            scr[STo + 2] = __fdiv_rn(mean, 0.5f);
        }
    }
}

// Fused per-row: max(Rn) -> Mi; P in REGISTERS; Zi; E-sums. exp via exp_fast.
__global__ __launch_bounds__(512) void k_MZE(float* __restrict__ scr,
                                             float* __restrict__ rowred) {
    __shared__ float red[512];
    __shared__ float LA[64], LB[32];
    __shared__ float Zsh;
    int i = blockIdx.x, t = threadIdx.x;
    int l = t >> 3, c = t & 7;
    const float* s2 = scr + S2o;
    float s1i = scr[S1o + i];
    float mu = scr[STo], sig = scr[STo + 1];
    int ebase = l * 128 + c;

    // phase A: Rn in registers + row max (order-free)
    float rn[16];
    float mx = -3.4e38f;
#pragma unroll
    for (int k = 0; k < 16; ++k) {
        float Rn = __fdiv_rn(__fsub_rn(lrelu32(__fadd_rn(s1i, s2[ebase + 8 * k])), mu), sig);
        rn[k] = Rn;
        mx = fmaxf(mx, Rn);
    }
    red[t] = mx;
    __syncthreads();
    for (int s = 256; s >= 1; s >>= 1) {
        if (t < s) red[t] = fmaxf(red[t], red[t + s]);
        __syncthreads();
    }
    float Mi = red[0];
    __syncthreads();

    // phase B: P in registers, chain sum (exact NP order)
    float p[16];
    p[0] = exp32cr(__fsub_rn(rn[0], Mi));
    float r = p[0];
#pragma unroll
    for (int k = 1; k < 16; ++k) {
        p[k] = exp32cr(__fsub_rn(rn[k], Mi));
        r = __fadd_rn(r, p[k]);
    }
    red[t] = r;
    ROW_REDUCE_TAIL(Zsh = src[0]; scr[Zo + i] = src[0]; scr[Mo + i] = Mi)
    __syncthreads();
    float Zi = Zsh;

    // phase C: E = P/Zi, same chain + leaf + tree order
    float e = __fdiv_rn(p[0], Zi);
#pragma unroll
    for (int k = 1; k < 16; ++k)
        e = __fadd_rn(e, __fdiv_rn(p[k], Zi));
    red[t] = e;
    ROW_REDUCE_TAIL(rowred[i] = src[0])
}

// One thread per row; 3 interleaved 32-step binary searches (ILP).
__global__ __launch_bounds__(256) void k_cut(float* __restrict__ scr) {
    int i = blockIdx.x * 256 + threadIdx.x;
    if (i >= Nn) return;
    float s1i = scr[S1o + i];
    float mu = scr[STo], sig = scr[STo + 1], thr = scr[STo + 2];
    float Mi = scr[Mo + i], Zi = scr[Zo + i];
    double thr_d = (double)thr;
    unsigned lo[3] = {0x00800000u, 0x00800000u, 0x00800000u};
    unsigned hi[3] = {0xFF800000u, 0xFF800000u, 0xFF800000u};
    for (int it = 0; it < 32; ++it) {
        unsigned mid[3];
        double m[3];
#pragma unroll
        for (int w = 0; w < 3; ++w) {
            mid[w] = lo[w] + ((hi[w] - lo[w]) >> 1);
            float s2v = key2f(mid[w]);
            float Rn = __fdiv_rn(__fsub_rn(lrelu32(__fadd_rn(s1i, s2v)), mu), sig);
            float P = exp32cr(__fsub_rn(Rn, Mi));
            float E = __fdiv_rn(P, Zi);
            m[w] = ((double)E - thr_d) / thr_d;
        }
        bool p0 = (m[0] >= -2.8e-8);
        bool p1 = (m[1] > 2.8e-8);
        bool p2 = (m[2] >= 1.75e-7);
        if (p0) hi[0] = mid[0]; else lo[0] = mid[0] + 1;
        if (p1) hi[1] = mid[1]; else lo[1] = mid[1] + 1;
        if (p2) hi[2] = mid[2]; else lo[2] = mid[2] + 1;
    }
    scr[Mo + i]  = __uint_as_float(lo[0]);
    scr[Zo + i]  = __uint_as_float(lo[1]);
    scr[RRo + i] = __uint_as_float(lo[2]);
}

// Pure streaming writer: 1024 blocks x 8 rows; nontemporal vec4 stores.
__global__ __launch_bounds__(256) void k_out(const float* __restrict__ scr,
                                             float* __restrict__ out) {
    int t = threadIdx.x;
    int r0 = blockIdx.x * 8;
    const float* s2 = scr + S2o;
    unsigned kA[8], kB[8], kC[8];
    long long rowbase[8];
#pragma unroll
    for (int rr = 0; rr < 8; ++rr) {
        int i = r0 + rr;
        kA[rr] = __float_as_uint(scr[Mo + i]);
        kB[rr] = __float_as_uint(scr[Zo + i]);
        kC[rr] = __float_as_uint(scr[RRo + i]);
        rowbase[rr] = (long long)i * Nn;
    }
    for (int ch = 0; ch < 8; ++ch) {
        int j0 = ch * 1024 + t * 4;
        nfloat4 sv = *reinterpret_cast<const nfloat4*>(s2 + j0);
        unsigned k0 = f2key(sv.x), k1 = f2key(sv.y), k2 = f2key(sv.z), k3 = f2key(sv.w);
#pragma unroll
        for (int rr = 0; rr < 8; ++rr) {
            unsigned a = kA[rr], b = kB[rr], cc = kC[rr];
            nfloat4 r;
            r.x = (k0 < a) ? 0.0f : (k0 < b) ? 1.0f : (k0 < cc) ? 0.0f : 1.0f;
            r.y = (k1 < a) ? 0.0f : (k1 < b) ? 1.0f : (k1 < cc) ? 0.0f : 1.0f;
            r.z = (k2 < a) ? 0.0f : (k2 < b) ? 1.0f : (k2 < cc) ? 0.0f : 1.0f;
            r.w = (k3 < a) ? 0.0f : (k3 < b) ? 1.0f : (k3 < cc) ? 0.0f : 1.0f;
            __builtin_nontemporal_store(r, reinterpret_cast<nfloat4*>(out + rowbase[rr] + j0));
        }
    }
}

extern "C" void kernel_launch(void* const* d_in, const int* in_sizes, int n_in,
                              void* d_out, int out_size, void* d_ws, size_t ws_size,
                              hipStream_t stream) {
    const float *X = nullptr, *Wr = nullptr, *ar = nullptr;
    for (int k = 0; k < n_in; ++k) {
        if      (in_sizes[k] == 1048576) X  = (const float*)d_in[k];
        else if (in_sizes[k] == 16384)   Wr = (const float*)d_in[k];
        else if (in_sizes[k] == 64)      ar = (const float*)d_in[k];
    }
    if (!X)  X  = (const float*)d_in[0];
    if (!Wr) Wr = (const float*)d_in[1];
    if (!ar) ar = (const float*)d_in[2];

    float* out = (float*)d_out;
    float* scr = (float*)d_ws;
    float* rowred = scr + RRo;

    k_s            <<<32,   256, 0, stream>>>(X, Wr, ar, scr);
    k_rows_stat8<0><<<1024, 512, 0, stream>>>(scr, rowred);
    k_tree<0>      <<<1,   1024, 0, stream>>>(rowred, scr);
    k_rows_stat8<1><<<1024, 512, 0, stream>>>(scr, rowred);
    k_tree<1>      <<<1,   1024, 0, stream>>>(rowred, scr);
    k_MZE          <<<Nn,   512, 0, stream>>>(scr, rowred);
    k_tree<2>      <<<1,   1024, 0, stream>>>(rowred, scr);
    k_cut          <<<32,   256, 0, stream>>>(scr);
    k_out          <<<1024, 256, 0, stream>>>(scr, out);
}

// Round 17
// 210.800 us; speedup vs baseline: 16.1040x; 1.0206x over previous
//
#include <hip/hip_runtime.h>
#include <math.h>

#define Nn 8192

// f32 scratch layout in d_ws (proven >= 207KB; we use ~165KB)
static constexpr int S1o = 256;          // 8192
static constexpr int S2o = S1o + Nn;     // 8448
static constexpr int Mo  = S2o + Nn;     // 16640: row max of Rn
static constexpr int Zo  = Mo + Nn;      // 24832: row sum of P
static constexpr int RRo = Zo + Nn;      // 33024: row reductions
static constexpr int STo = RRo + Nn;     // 41216: mu, sig, thr

typedef float nfloat4 __attribute__((ext_vector_type(4)));  // clang-native vec4

// ---- bit-exact f32 helpers ----
__device__ __forceinline__ float lrelu32(float z) {
    return (z >= 0.0f) ? z : __fmul_rn(0.01f, z);
}

// Branch-free f64 exp, rel err ~2^-49 (validated bit-compatible in r16).
__device__ __forceinline__ double exp_fast(double x) {
    x = fmin(fmax(x, -700.0), 700.0);
    const double INVLN2 = 1.44269504088896338700e+00;
    const double LN2HI  = 6.93147180369123816490e-01;
    const double LN2LO  = 1.90821492927058770002e-10;
    double nd = rint(x * INVLN2);
    double r  = fma(-nd, LN2HI, x);
    r = fma(-nd, LN2LO, r);
    double p = 1.56192069685862264622e-10;
    p = fma(p, r, 2.08767569878680989792e-09);
    p = fma(p, r, 2.50521083854417187751e-08);
    p = fma(p, r, 2.75573192239858906526e-07);
    p = fma(p, r, 2.75573192239858925110e-06);
    p = fma(p, r, 2.48015873015873015873e-05);
    p = fma(p, r, 1.98412698412698412698e-04);
    p = fma(p, r, 1.38888888888888894069e-03);
    p = fma(p, r, 8.33333333333333321769e-03);
    p = fma(p, r, 4.16666666666666643537e-02);
    p = fma(p, r, 1.66666666666666657415e-01);
    p = fma(p, r, 5.00000000000000000000e-01);
    p = fma(p, r, 1.0);
    p = fma(p, r, 1.0);
    long long n = (long long)nd;
    double sc = __longlong_as_double((n + 1023LL) << 52);
    return p * sc;
}
__device__ __forceinline__ float exp32cr(float x) {
    return (float)exp_fast((double)x);
}

__device__ float blas_dot(const float* __restrict__ a, const float* __restrict__ x, int n) {
    float lane[8];
#pragma unroll
    for (int l = 0; l < 8; ++l) lane[l] = 0.0f;
    for (int k = 0; k < n; k += 8) {
#pragma unroll
        for (int l = 0; l < 8; ++l) lane[l] = __fmaf_rn(a[k + l], x[k + l], lane[l]);
    }
    float s0 = __fadd_rn(lane[0], lane[4]);
    float s1 = __fadd_rn(lane[1], lane[5]);
    float s2 = __fadd_rn(lane[2], lane[6]);
    float s3 = __fadd_rn(lane[3], lane[7]);
    return __fadd_rn(__fadd_rn(s0, s1), __fadd_rn(s2, s3));
}

// sortable-key bijection for f32
__device__ __forceinline__ unsigned f2key(float f) {
    unsigned u = __float_as_uint(f);
    return (u & 0x80000000u) ? ~u : (u | 0x80000000u);
}
__device__ __forceinline__ float key2f(unsigned k) {
    unsigned u = (k & 0x80000000u) ? (k & 0x7FFFFFFFu) : ~k;
    return __uint_as_float(u);
}

// ---- reduction tail: red[512] -> leaf-combine -> 6-level IN-WAVE tree ----
// Same (2t,2t+1) f32 adds as the LDS version (bit-identical), zero barriers
// inside the tree. `total` is defined for RESULT_STMT (t==0 only).
#define ROW_REDUCE_TAIL_SHFL(RESULT_STMT)                                     \
    {                                                                         \
        __syncthreads();                                                      \
        if (t < 64) {                                                         \
            float sl = __fadd_rn(__fadd_rn(red[t * 8 + 0], red[t * 8 + 1]),   \
                                 __fadd_rn(red[t * 8 + 2], red[t * 8 + 3]));  \
            float sr = __fadd_rn(__fadd_rn(red[t * 8 + 4], red[t * 8 + 5]),   \
                                 __fadd_rn(red[t * 8 + 6], red[t * 8 + 7]));  \
            float v = __fadd_rn(sl, sr);                                      \
            _Pragma("unroll") for (int s_ = 32; s_ >= 1; s_ >>= 1) {          \
                float a_ = __shfl(v, (2 * t) & 63);                           \
                float b_ = __shfl(v, (2 * t + 1) & 63);                       \
                if (t < s_) v = __fadd_rn(a_, b_);                            \
            }                                                                 \
            if (t == 0) { float total = v; RESULT_STMT; }                     \
        }                                                                     \
        __syncthreads();                                                      \
    }

// K1: fused w + s. 32 blocks x 256.
__global__ __launch_bounds__(256) void k_s(const float* __restrict__ X,
                                           const float* __restrict__ Wr,
                                           const float* __restrict__ ar,
                                           float* __restrict__ scr) {
    __shared__ float w1[128], w2[128];
    int t = threadIdx.x;
    if (t < 128) {
        w1[t] = blas_dot(Wr + t * 64, ar, 64);
        w2[t] = blas_dot(Wr + (128 + t) * 64, ar, 64);
    }
    __syncthreads();
    int i = blockIdx.x * 256 + t;
    scr[S1o + i] = blas_dot(X + i * 128, w1, 128);
    scr[S2o + i] = blas_dot(X + i * 128, w2, 128);
}

// stats pass, 1024 blocks x 8 rows; s2 slice in registers, reused per row.
template <int MODE>
__global__ __launch_bounds__(512) void k_rows_stat8(const float* __restrict__ scr,
                                                    float* __restrict__ rowred) {
    __shared__ float red[512];
    int r0 = blockIdx.x * 8, t = threadIdx.x;
    int l = t >> 3, c = t & 7;
    const float* s2 = scr + S2o;
    int ebase = l * 128 + c;
    float sv[16];
#pragma unroll
    for (int k = 0; k < 16; ++k) sv[k] = s2[ebase + 8 * k];
    float mu = (MODE == 1) ? scr[STo] : 0.0f;
    for (int rr = 0; rr < 8; ++rr) {
        float s1i = scr[S1o + r0 + rr];
        float r;
        if (MODE == 0) {
            r = lrelu32(__fadd_rn(s1i, sv[0]));
#pragma unroll
            for (int k = 1; k < 16; ++k)
                r = __fadd_rn(r, lrelu32(__fadd_rn(s1i, sv[k])));
        } else {
            float d0 = __fsub_rn(lrelu32(__fadd_rn(s1i, sv[0])), mu);
            r = __fmul_rn(d0, d0);
#pragma unroll
            for (int k = 1; k < 16; ++k) {
                float d = __fsub_rn(lrelu32(__fadd_rn(s1i, sv[k])), mu);
                r = __fadd_rn(r, __fmul_rn(d, d));
            }
        }
        red[t] = r;
        ROW_REDUCE_TAIL_SHFL(rowred[r0 + rr] = total)
    }
}

template <int MODE>
__global__ __launch_bounds__(1024) void k_tree(const float* __restrict__ rowred,
                                               float* __restrict__ scr) {
    __shared__ float A[8192];
    __shared__ float B[4096];
    int t = threadIdx.x;  // 1024
    for (int idx = t; idx < 8192; idx += 1024) A[idx] = rowred[idx];
    __syncthreads();
    float* src = A;
    float* dst = B;
    for (int s = 4096; s >= 1; s >>= 1) {
        for (int idx = t; idx < s; idx += 1024)
            dst[idx] = __fadd_rn(src[2 * idx], src[2 * idx + 1]);
        __syncthreads();
        float* tmp = src; src = dst; dst = tmp;
    }
    if (t == 0) {
        float total = src[0];
        if (MODE == 0) {
            scr[STo] = __fdiv_rn(total, 67108864.0f);
        } else if (MODE == 1) {
            float var = __fdiv_rn(total, 67108864.0f);
            scr[STo + 1] = __fadd_rn(__fsqrt_rn(var), 1e-5f);
        } else {
            float mean = __fdiv_rn(total, 67108864.0f);
            scr[STo + 2] = __fdiv_rn(mean, 0.5f);
        }
    }
}

// Fused per-row: max(Rn)->Mi (shfl_xor, order-free); P in registers; Zi;
// E-sums. Sum order identical to numpy (chain + leaf + (2t,2t+1) tree).
__global__ __launch_bounds__(512) void k_MZE(float* __restrict__ scr,
                                             float* __restrict__ rowred) {
    __shared__ float red[512];
    __shared__ float wmax[8];
    __shared__ float Zsh;
    int i = blockIdx.x, t = threadIdx.x;
    int l = t >> 3, c = t & 7;
    const float* s2 = scr + S2o;
    float s1i = scr[S1o + i];
    float mu = scr[STo], sig = scr[STo + 1];
    int ebase = l * 128 + c;

    // phase A: Rn in registers + row max (order-free -> shuffle reduce)
    float rn[16];
    float mx = -3.4e38f;
#pragma unroll
    for (int k = 0; k < 16; ++k) {
        float Rn = __fdiv_rn(__fsub_rn(lrelu32(__fadd_rn(s1i, s2[ebase + 8 * k])), mu), sig);
        rn[k] = Rn;
        mx = fmaxf(mx, Rn);
    }
#pragma unroll
    for (int o = 32; o > 0; o >>= 1) mx = fmaxf(mx, __shfl_xor(mx, o));
    if ((t & 63) == 0) wmax[t >> 6] = mx;
    __syncthreads();
    float Mi = fmaxf(fmaxf(fmaxf(wmax[0], wmax[1]), fmaxf(wmax[2], wmax[3])),
                     fmaxf(fmaxf(wmax[4], wmax[5]), fmaxf(wmax[6], wmax[7])));

    // phase B: P in registers, chain sum (exact NP order)
    float p[16];
    p[0] = exp32cr(__fsub_rn(rn[0], Mi));
    float r = p[0];
#pragma unroll
    for (int k = 1; k < 16; ++k) {
        p[k] = exp32cr(__fsub_rn(rn[k], Mi));
        r = __fadd_rn(r, p[k]);
    }
    red[t] = r;
    ROW_REDUCE_TAIL_SHFL(Zsh = total; scr[Zo + i] = total; scr[Mo + i] = Mi)
    float Zi = Zsh;

    // phase C: E = P/Zi, same chain + leaf + tree order
    float e = __fdiv_rn(p[0], Zi);
#pragma unroll
    for (int k = 1; k < 16; ++k)
        e = __fadd_rn(e, __fdiv_rn(p[k], Zi));
    red[t] = e;
    ROW_REDUCE_TAIL_SHFL(rowred[i] = total)
}

// k_out with fused cut: threads 0..23 binary-search the 3 monotone cutoffs
// for this block's 8 rows (identical probe arithmetic to r15's k_cut), then
// all 256 threads stream-write with nontemporal vec4 stores.
__global__ __launch_bounds__(256) void k_out(const float* __restrict__ scr,
                                             float* __restrict__ out) {
    __shared__ unsigned kcut[8][3];
    int t = threadIdx.x;
    int r0 = blockIdx.x * 8;
    float mu = scr[STo], sig = scr[STo + 1], thr = scr[STo + 2];
    if (t < 24) {
        int rr = t / 3, w = t - rr * 3;
        int i = r0 + rr;
        float s1i = scr[S1o + i];
        float Mi = scr[Mo + i], Zi = scr[Zo + i];
        double thr_d = (double)thr;
        unsigned lo = 0x00800000u;   // key(-FLT_MAX)
        unsigned hi = 0xFF800000u;   // key(+inf), exclusive
        while (lo < hi) {
            unsigned mid = lo + ((hi - lo) >> 1);
            float s2v = key2f(mid);
            float Rn = __fdiv_rn(__fsub_rn(lrelu32(__fadd_rn(s1i, s2v)), mu), sig);
            float P = exp32cr(__fsub_rn(Rn, Mi));
            float E = __fdiv_rn(P, Zi);
            double m = ((double)E - thr_d) / thr_d;
            bool pred = (w == 0) ? (m >= -2.8e-8)
                      : (w == 1) ? (m > 2.8e-8)
                                 : (m >= 1.75e-7);
            if (pred) hi = mid; else lo = mid + 1;
        }
        kcut[rr][w] = lo;
    }
    __syncthreads();
    unsigned kA[8], kB[8], kC[8];
    long long rowbase[8];
#pragma unroll
    for (int rr = 0; rr < 8; ++rr) {
        kA[rr] = kcut[rr][0];
        kB[rr] = kcut[rr][1];
        kC[rr] = kcut[rr][2];
        rowbase[rr] = (long long)(r0 + rr) * Nn;
    }
    const float* s2 = scr + S2o;
    for (int ch = 0; ch < 8; ++ch) {
        int j0 = ch * 1024 + t * 4;
        nfloat4 sv = *reinterpret_cast<const nfloat4*>(s2 + j0);
        unsigned k0 = f2key(sv.x), k1 = f2key(sv.y), k2 = f2key(sv.z), k3 = f2key(sv.w);
#pragma unroll
        for (int rr = 0; rr < 8; ++rr) {
            unsigned a = kA[rr], b = kB[rr], cc = kC[rr];
            nfloat4 r;
            r.x = (k0 < a) ? 0.0f : (k0 < b) ? 1.0f : (k0 < cc) ? 0.0f : 1.0f;
            r.y = (k1 < a) ? 0.0f : (k1 < b) ? 1.0f : (k1 < cc) ? 0.0f : 1.0f;
            r.z = (k2 < a) ? 0.0f : (k2 < b) ? 1.0f : (k2 < cc) ? 0.0f : 1.0f;
            r.w = (k3 < a) ? 0.0f : (k3 < b) ? 1.0f : (k3 < cc) ? 0.0f : 1.0f;
            __builtin_nontemporal_store(r, reinterpret_cast<nfloat4*>(out + rowbase[rr] + j0));
        }
    }
}

extern "C" void kernel_launch(void* const* d_in, const int* in_sizes, int n_in,
                              void* d_out, int out_size, void* d_ws, size_t ws_size,
                              hipStream_t stream) {
    const float *X = nullptr, *Wr = nullptr, *ar = nullptr;
    for (int k = 0; k < n_in; ++k) {
        if      (in_sizes[k] == 1048576) X  = (const float*)d_in[k];
        else if (in_sizes[k] == 16384)   Wr = (const float*)d_in[k];
        else if (in_sizes[k] == 64)      ar = (const float*)d_in[k];
    }
    if (!X)  X  = (const float*)d_in[0];
    if (!Wr) Wr = (const float*)d_in[1];
    if (!ar) ar = (const float*)d_in[2];

    float* out = (float*)d_out;
    float* scr = (float*)d_ws;
    float* rowred = scr + RRo;

    k_s            <<<32,   256, 0, stream>>>(X, Wr, ar, scr);
    k_rows_stat8<0><<<1024, 512, 0, stream>>>(scr, rowred);
    k_tree<0>      <<<1,   1024, 0, stream>>>(rowred, scr);
    k_rows_stat8<1><<<1024, 512, 0, stream>>>(scr, rowred);
    k_tree<1>      <<<1,   1024, 0, stream>>>(rowred, scr);
    k_MZE          <<<Nn,   512, 0, stream>>>(scr, rowred);
    k_tree<2>      <<<1,   1024, 0, stream>>>(rowred, scr);
    k_out          <<<1024, 256, 0, stream>>>(scr, out);
}

// Round 18
// 207.923 us; speedup vs baseline: 16.3268x; 1.0138x over previous
//
#include <hip/hip_runtime.h>
#include <math.h>

#define Nn 8192

// f32 scratch layout in d_ws
static constexpr int S1o = 256;          // 8192
static constexpr int S2o = S1o + Nn;     // 8448
static constexpr int Mo  = S2o + Nn;     // 16640: row max of Rn
static constexpr int Zo  = Mo + Nn;      // 24832: row sum of P
static constexpr int RRo = Zo + Nn;      // 33024: row reductions
static constexpr int STo = RRo + Nn;     // 41216: mu, sig, thr

typedef float nfloat4 __attribute__((ext_vector_type(4)));

// ---- bit-exact f32 helpers ----
__device__ __forceinline__ float lrelu32(float z) {
    return (z >= 0.0f) ? z : __fmul_rn(0.01f, z);
}

// Branch-free f64 exp, rel err ~2^-49 (validated bit-compatible r16/r17).
__device__ __forceinline__ double exp_fast(double x) {
    x = fmin(fmax(x, -700.0), 700.0);
    const double INVLN2 = 1.44269504088896338700e+00;
    const double LN2HI  = 6.93147180369123816490e-01;
    const double LN2LO  = 1.90821492927058770002e-10;
    double nd = rint(x * INVLN2);
    double r  = fma(-nd, LN2HI, x);
    r = fma(-nd, LN2LO, r);
    double p = 1.56192069685862264622e-10;
    p = fma(p, r, 2.08767569878680989792e-09);
    p = fma(p, r, 2.50521083854417187751e-08);
    p = fma(p, r, 2.75573192239858906526e-07);
    p = fma(p, r, 2.75573192239858925110e-06);
    p = fma(p, r, 2.48015873015873015873e-05);
    p = fma(p, r, 1.98412698412698412698e-04);
    p = fma(p, r, 1.38888888888888894069e-03);
    p = fma(p, r, 8.33333333333333321769e-03);
    p = fma(p, r, 4.16666666666666643537e-02);
    p = fma(p, r, 1.66666666666666657415e-01);
    p = fma(p, r, 5.00000000000000000000e-01);
    p = fma(p, r, 1.0);
    p = fma(p, r, 1.0);
    long long n = (long long)nd;
    double sc = __longlong_as_double((n + 1023LL) << 52);
    return p * sc;
}
__device__ __forceinline__ float exp32cr(float x) {
    return (float)exp_fast((double)x);
}

__device__ float blas_dot(const float* __restrict__ a, const float* __restrict__ x, int n) {
    float lane[8];
#pragma unroll
    for (int l = 0; l < 8; ++l) lane[l] = 0.0f;
    for (int k = 0; k < n; k += 8) {
#pragma unroll
        for (int l = 0; l < 8; ++l) lane[l] = __fmaf_rn(a[k + l], x[k + l], lane[l]);
    }
    float s0 = __fadd_rn(lane[0], lane[4]);
    float s1 = __fadd_rn(lane[1], lane[5]);
    float s2 = __fadd_rn(lane[2], lane[6]);
    float s3 = __fadd_rn(lane[3], lane[7]);
    return __fadd_rn(__fadd_rn(s0, s1), __fadd_rn(s2, s3));
}

// sortable-key bijection for f32
__device__ __forceinline__ unsigned f2key(float f) {
    unsigned u = __float_as_uint(f);
    return (u & 0x80000000u) ? ~u : (u | 0x80000000u);
}
__device__ __forceinline__ float key2f(unsigned k) {
    unsigned u = (k & 0x80000000u) ? (k & 0x7FFFFFFFu) : ~k;
    return __uint_as_float(u);
}

// red[512] -> leaf-combine -> 6-level in-wave tree (bit-identical pairing).
#define ROW_REDUCE_TAIL_SHFL(RESULT_STMT)                                     \
    {                                                                         \
        __syncthreads();                                                      \
        if (t < 64) {                                                         \
            float sl = __fadd_rn(__fadd_rn(red[t * 8 + 0], red[t * 8 + 1]),   \
                                 __fadd_rn(red[t * 8 + 2], red[t * 8 + 3]));  \
            float sr = __fadd_rn(__fadd_rn(red[t * 8 + 4], red[t * 8 + 5]),   \
                                 __fadd_rn(red[t * 8 + 6], red[t * 8 + 7]));  \
            float v = __fadd_rn(sl, sr);                                      \
            _Pragma("unroll") for (int s_ = 32; s_ >= 1; s_ >>= 1) {          \
                float a_ = __shfl(v, (2 * t) & 63);                           \
                float b_ = __shfl(v, (2 * t + 1) & 63);                       \
                if (t < s_) v = __fadd_rn(a_, b_);                            \
            }                                                                 \
            if (t == 0) { float total = v; RESULT_STMT; }                     \
        }                                                                     \
        __syncthreads();                                                      \
    }

// K1: fused w + s. 32 blocks x 256.
__global__ __launch_bounds__(256) void k_s(const float* __restrict__ X,
                                           const float* __restrict__ Wr,
                                           const float* __restrict__ ar,
                                           float* __restrict__ scr) {
    __shared__ float w1[128], w2[128];
    int t = threadIdx.x;
    if (t < 128) {
        w1[t] = blas_dot(Wr + t * 64, ar, 64);
        w2[t] = blas_dot(Wr + (128 + t) * 64, ar, 64);
    }
    __syncthreads();
    int i = blockIdx.x * 256 + t;
    scr[S1o + i] = blas_dot(X + i * 128, w1, 128);
    scr[S2o + i] = blas_dot(X + i * 128, w2, 128);
}

// stats pass, 512 blocks x 16 rows; s2 slice in registers, reused per row.
template <int MODE>
__global__ __launch_bounds__(512) void k_rows_stat16(const float* __restrict__ scr,
                                                     float* __restrict__ rowred) {
    __shared__ float red[512];
    int r0 = blockIdx.x * 16, t = threadIdx.x;
    int l = t >> 3, c = t & 7;
    const float* s2 = scr + S2o;
    int ebase = l * 128 + c;
    float sv[16];
#pragma unroll
    for (int k = 0; k < 16; ++k) sv[k] = s2[ebase + 8 * k];
    float mu = (MODE == 1) ? scr[STo] : 0.0f;
    for (int rr = 0; rr < 16; ++rr) {
        float s1i = scr[S1o + r0 + rr];
        float r;
        if (MODE == 0) {
            r = lrelu32(__fadd_rn(s1i, sv[0]));
#pragma unroll
            for (int k = 1; k < 16; ++k)
                r = __fadd_rn(r, lrelu32(__fadd_rn(s1i, sv[k])));
        } else {
            float d0 = __fsub_rn(lrelu32(__fadd_rn(s1i, sv[0])), mu);
            r = __fmul_rn(d0, d0);
#pragma unroll
            for (int k = 1; k < 16; ++k) {
                float d = __fsub_rn(lrelu32(__fadd_rn(s1i, sv[k])), mu);
                r = __fadd_rn(r, __fmul_rn(d, d));
            }
        }
        red[t] = r;
        ROW_REDUCE_TAIL_SHFL(rowred[r0 + rr] = total)
    }
}

template <int MODE>
__global__ __launch_bounds__(1024) void k_tree(const float* __restrict__ rowred,
                                               float* __restrict__ scr) {
    __shared__ float A[8192];
    __shared__ float B[4096];
    int t = threadIdx.x;  // 1024
    for (int idx = t; idx < 8192; idx += 1024) A[idx] = rowred[idx];
    __syncthreads();
    float* src = A;
    float* dst = B;
    for (int s = 4096; s >= 1; s >>= 1) {
        for (int idx = t; idx < s; idx += 1024)
            dst[idx] = __fadd_rn(src[2 * idx], src[2 * idx + 1]);
        __syncthreads();
        float* tmp = src; src = dst; dst = tmp;
    }
    if (t == 0) {
        float total = src[0];
        if (MODE == 0) {
            scr[STo] = __fdiv_rn(total, 67108864.0f);
        } else if (MODE == 1) {
            float var = __fdiv_rn(total, 67108864.0f);
            scr[STo + 1] = __fadd_rn(__fsqrt_rn(var), 1e-5f);
        } else {
            float mean = __fdiv_rn(total, 67108864.0f);
            scr[STo + 2] = __fdiv_rn(mean, 0.5f);
        }
    }
}

// Fused per-row M/Z/E pass, 2 rows/block; s2 slice in registers reused.
// Cross-row LDS hazards (Zsh, wmax) ordered by the reduce-tail barriers.
__global__ __launch_bounds__(512) void k_MZE2(float* __restrict__ scr,
                                              float* __restrict__ rowred) {
    __shared__ float red[512];
    __shared__ float wmax[8];
    __shared__ float Zsh;
    int t = threadIdx.x;
    int l = t >> 3, c = t & 7;
    const float* s2 = scr + S2o;
    float mu = scr[STo], sig = scr[STo + 1];
    int ebase = l * 128 + c;
    float sv[16];
#pragma unroll
    for (int k = 0; k < 16; ++k) sv[k] = s2[ebase + 8 * k];

    for (int rr = 0; rr < 2; ++rr) {
        int i = blockIdx.x * 2 + rr;
        float s1i = scr[S1o + i];

        // phase A: Rn in registers + row max (order-free)
        float rn[16];
        float mx = -3.4e38f;
#pragma unroll
        for (int k = 0; k < 16; ++k) {
            float Rn = __fdiv_rn(__fsub_rn(lrelu32(__fadd_rn(s1i, sv[k])), mu), sig);
            rn[k] = Rn;
            mx = fmaxf(mx, Rn);
        }
#pragma unroll
        for (int o = 32; o > 0; o >>= 1) mx = fmaxf(mx, __shfl_xor(mx, o));
        if ((t & 63) == 0) wmax[t >> 6] = mx;
        __syncthreads();
        float Mi = fmaxf(fmaxf(fmaxf(wmax[0], wmax[1]), fmaxf(wmax[2], wmax[3])),
                         fmaxf(fmaxf(wmax[4], wmax[5]), fmaxf(wmax[6], wmax[7])));

        // phase B: P in registers, chain sum (exact NP order)
        float p[16];
        p[0] = exp32cr(__fsub_rn(rn[0], Mi));
        float r = p[0];
#pragma unroll
        for (int k = 1; k < 16; ++k) {
            p[k] = exp32cr(__fsub_rn(rn[k], Mi));
            r = __fadd_rn(r, p[k]);
        }
        red[t] = r;
        ROW_REDUCE_TAIL_SHFL(Zsh = total; scr[Zo + i] = total; scr[Mo + i] = Mi)
        float Zi = Zsh;

        // phase C: E = P/Zi, same chain + leaf + tree order
        float e = __fdiv_rn(p[0], Zi);
#pragma unroll
        for (int k = 1; k < 16; ++k)
            e = __fadd_rn(e, __fdiv_rn(p[k], Zi));
        red[t] = e;
        ROW_REDUCE_TAIL_SHFL(rowred[i] = total)
    }
}

// k_out with fused cut: threads 0..23 binary-search 3 monotone cutoffs for
// the block's 8 rows, then 256 threads stream-write nontemporal vec4.
__global__ __launch_bounds__(256) void k_out(const float* __restrict__ scr,
                                             float* __restrict__ out) {
    __shared__ unsigned kcut[8][3];
    int t = threadIdx.x;
    int r0 = blockIdx.x * 8;
    float mu = scr[STo], sig = scr[STo + 1], thr = scr[STo + 2];
    if (t < 24) {
        int rr = t / 3, w = t - rr * 3;
        int i = r0 + rr;
        float s1i = scr[S1o + i];
        float Mi = scr[Mo + i], Zi = scr[Zo + i];
        double thr_d = (double)thr;
        unsigned lo = 0x00800000u;
        unsigned hi = 0xFF800000u;
        while (lo < hi) {
            unsigned mid = lo + ((hi - lo) >> 1);
            float s2v = key2f(mid);
            float Rn = __fdiv_rn(__fsub_rn(lrelu32(__fadd_rn(s1i, s2v)), mu), sig);
            float P = exp32cr(__fsub_rn(Rn, Mi));
            float E = __fdiv_rn(P, Zi);
            double m = ((double)E - thr_d) / thr_d;
            bool pred = (w == 0) ? (m >= -2.8e-8)
                      : (w == 1) ? (m > 2.8e-8)
                                 : (m >= 1.75e-7);
            if (pred) hi = mid; else lo = mid + 1;
        }
        kcut[rr][w] = lo;
    }
    __syncthreads();
    unsigned kA[8], kB[8], kC[8];
    long long rowbase[8];
#pragma unroll
    for (int rr = 0; rr < 8; ++rr) {
        kA[rr] = kcut[rr][0];
        kB[rr] = kcut[rr][1];
        kC[rr] = kcut[rr][2];
        rowbase[rr] = (long long)(r0 + rr) * Nn;
    }
    const float* s2 = scr + S2o;
    for (int ch = 0; ch < 8; ++ch) {
        int j0 = ch * 1024 + t * 4;
        nfloat4 sv = *reinterpret_cast<const nfloat4*>(s2 + j0);
        unsigned k0 = f2key(sv.x), k1 = f2key(sv.y), k2 = f2key(sv.z), k3 = f2key(sv.w);
#pragma unroll
        for (int rr = 0; rr < 8; ++rr) {
            unsigned a = kA[rr], b = kB[rr], cc = kC[rr];
            nfloat4 r;
            r.x = (k0 < a) ? 0.0f : (k0 < b) ? 1.0f : (k0 < cc) ? 0.0f : 1.0f;
            r.y = (k1 < a) ? 0.0f : (k1 < b) ? 1.0f : (k1 < cc) ? 0.0f : 1.0f;
            r.z = (k2 < a) ? 0.0f : (k2 < b) ? 1.0f : (k2 < cc) ? 0.0f : 1.0f;
            r.w = (k3 < a) ? 0.0f : (k3 < b) ? 1.0f : (k3 < cc) ? 0.0f : 1.0f;
            __builtin_nontemporal_store(r, reinterpret_cast<nfloat4*>(out + rowbase[rr] + j0));
        }
    }
}

extern "C" void kernel_launch(void* const* d_in, const int* in_sizes, int n_in,
                              void* d_out, int out_size, void* d_ws, size_t ws_size,
                              hipStream_t stream) {
    const float *X = nullptr, *Wr = nullptr, *ar = nullptr;
    for (int k = 0; k < n_in; ++k) {
        if      (in_sizes[k] == 1048576) X  = (const float*)d_in[k];
        else if (in_sizes[k] == 16384)   Wr = (const float*)d_in[k];
        else if (in_sizes[k] == 64)      ar = (const float*)d_in[k];
    }
    if (!X)  X  = (const float*)d_in[0];
    if (!Wr) Wr = (const float*)d_in[1];
    if (!ar) ar = (const float*)d_in[2];

    float* out = (float*)d_out;
    float* scr = (float*)d_ws;
    float* rowred = scr + RRo;

    k_s             <<<32,   256, 0, stream>>>(X, Wr, ar, scr);
    k_rows_stat16<0><<<512,  512, 0, stream>>>(scr, rowred);
    k_tree<0>       <<<1,   1024, 0, stream>>>(rowred, scr);
    k_rows_stat16<1><<<512,  512, 0, stream>>>(scr, rowred);
    k_tree<1>       <<<1,   1024, 0, stream>>>(rowred, scr);
    k_MZE2          <<<4096, 512, 0, stream>>>(scr, rowred);
    k_tree<2>       <<<1,   1024, 0, stream>>>(rowred, scr);
    k_out           <<<1024, 256, 0, stream>>>(scr, out);
}